// Round 2
// baseline (248.317 us; speedup 1.0000x reference)
//
#include <hip/hip_runtime.h>

#define HW 4096
#define NCH 256
#define DIM 128
#define NPROTO 512

typedef __attribute__((ext_vector_type(4))) float f32x4;
typedef __attribute__((ext_vector_type(8))) short s16x8;
typedef __attribute__((ext_vector_type(4))) unsigned u32x4;

__device__ __forceinline__ unsigned short f2bf(float f) {
  union { float f; unsigned u; } v; v.f = f;
  unsigned r = v.u + 0x7fffu + ((v.u >> 16) & 1u);
  return (unsigned short)(r >> 16);
}

// ---------------------------------------------------------------------------
// prep: blocks 0..7: prototypes -> bf16 chunked Pr[ch][n][32] (ch = d/32) +
//       p_norm2.  blocks 8..9: W -> bf16 chunked Wr[ch][d][32] (ch = c/32).
// Both layouts give 64B rows so MFMA B-fragments load directly from global:
//   frag(row, koff=8*l4) = base + (ch*ROWS + row)*32 + 8*l4     (bf16 units)
// ---------------------------------------------------------------------------
__global__ __launch_bounds__(256) void prep_kernel(const float* __restrict__ P,
                                                   const float* __restrict__ Wm,
                                                   unsigned short* __restrict__ Pr,
                                                   unsigned short* __restrict__ Wr,
                                                   float* __restrict__ pn2) {
  const int tid = threadIdx.x;
  if (blockIdx.x < 8) {
    const int n  = blockIdx.x * 64 + (tid >> 2);
    const int qt = tid & 3;
    const float* row = P + n * DIM + qt * 32;
    unsigned short* dst = Pr + ((size_t)qt * NPROTO + n) * 32;
    float ssq = 0.f;
#pragma unroll
    for (int u = 0; u < 8; ++u) {
      f32x4 v = *(const f32x4*)(row + 4 * u);
      ssq += v.x * v.x + v.y * v.y + v.z * v.z + v.w * v.w;
      dst[4 * u + 0] = f2bf(v.x);
      dst[4 * u + 1] = f2bf(v.y);
      dst[4 * u + 2] = f2bf(v.z);
      dst[4 * u + 3] = f2bf(v.w);
    }
    ssq += __shfl_xor(ssq, 1);
    ssq += __shfl_xor(ssq, 2);
    if (qt == 0) pn2[n] = ssq;
  } else {
#pragma unroll
    for (int it = 0; it < 2; ++it) {
      const int p  = (blockIdx.x - 8) * 256 + tid + 512 * it;  // 0..1023
      const int d  = p >> 3;
      const int ch = p & 7;
      const float* src = Wm + d * NCH + 32 * ch;
      unsigned short* dst = Wr + ((size_t)ch * DIM + d) * 32;
#pragma unroll
      for (int u = 0; u < 8; ++u) {
        f32x4 v = *(const f32x4*)(src + 4 * u);
        dst[4 * u + 0] = f2bf(v.x);
        dst[4 * u + 1] = f2bf(v.y);
        dst[4 * u + 2] = f2bf(v.z);
        dst[4 * u + 3] = f2bf(v.w);
      }
    }
  }
}

// ---------------------------------------------------------------------------
// proj: q[t][d] = sum_c x[.,c,.,.] * W[d,c] + b[d]  -> bf16 [65536][128]
// Block 512 thr, tile 128 pix x 128 d. x staged to LDS transposed (pix-major)
// in 32-channel chunks, double-buffered, ONE barrier per chunk. Each thread:
// 8 coalesced scalar loads (1 pixel, 8 channels) -> pack -> 1 ds_write_b128
// (stride 40 bf16 => conflict-free bank starts). W fragments load directly
// from global bf16 Wr (L1/L2-resident, 64KB).
// ---------------------------------------------------------------------------
__global__ __launch_bounds__(512, 2) void proj_kernel(const float* __restrict__ x,
                                                      const unsigned short* __restrict__ Wr,
                                                      const float* __restrict__ bias,
                                                      unsigned short* __restrict__ qbf) {
  __shared__ __align__(16) unsigned short x_s[2][128 * 40];
  const int tid  = threadIdx.x;
  const int p0   = blockIdx.x * 128;
  const int nimg = p0 >> 12;
  const int hw0  = p0 & 4095;
  const float* xbase = x + (size_t)nimg * NCH * HW + hw0;
  const int wave = tid >> 6, lane = tid & 63;
  const int l15 = lane & 15, l4 = lane >> 4;
  const int pix = tid & 127;   // pixel this thread stages
  const int qq  = tid >> 7;    // channel octet 0..3 within 32-ch chunk

  f32x4 acc[8];
#pragma unroll
  for (int j = 0; j < 8; ++j)
#pragma unroll
    for (int r = 0; r < 4; ++r) acc[j][r] = 0.f;

  // ---- stage chunk 0
  {
    const float* src = xbase + (size_t)(8 * qq) * HW + pix;
    u32x4 vv;
#pragma unroll
    for (int jj = 0; jj < 4; ++jj) {
      float f0 = src[(size_t)(2 * jj) * HW];
      float f1 = src[(size_t)(2 * jj + 1) * HW];
      vv[jj] = (unsigned)f2bf(f0) | ((unsigned)f2bf(f1) << 16);
    }
    *(u32x4*)&x_s[0][pix * 40 + 8 * qq] = vv;
  }
  __syncthreads();

  const int m = 16 * wave + l15;
  for (int ch = 0; ch < 8; ++ch) {
    if (ch < 7) {  // prefetch chunk ch+1 into other buffer
      const float* src = xbase + (size_t)(32 * (ch + 1) + 8 * qq) * HW + pix;
      u32x4 vv;
#pragma unroll
      for (int jj = 0; jj < 4; ++jj) {
        float f0 = src[(size_t)(2 * jj) * HW];
        float f1 = src[(size_t)(2 * jj + 1) * HW];
        vv[jj] = (unsigned)f2bf(f0) | ((unsigned)f2bf(f1) << 16);
      }
      *(u32x4*)&x_s[(ch + 1) & 1][pix * 40 + 8 * qq] = vv;
    }
    // ---- compute on buffer ch&1
    s16x8 a = *(const s16x8*)&x_s[ch & 1][m * 40 + 8 * l4];
    const unsigned short* wbase = Wr + ((size_t)ch * DIM + l15) * 32 + 8 * l4;
#pragma unroll
    for (int j = 0; j < 8; ++j) {
      s16x8 b = *(const s16x8*)(wbase + (size_t)(16 * j) * 32);
      acc[j] = __builtin_amdgcn_mfma_f32_16x16x32_bf16(a, b, acc[j], 0, 0, 0);
    }
    __syncthreads();
  }

  // epilogue: C/D layout col=lane&15 (=d), row=(lane>>4)*4+reg (=pix)
  const int mb = 16 * wave + 4 * l4;
#pragma unroll
  for (int j = 0; j < 8; ++j) {
    const int d = 16 * j + l15;
    const float bv = bias[d];
#pragma unroll
    for (int r = 0; r < 4; ++r)
      qbf[(size_t)(p0 + mb + r) * DIM + d] = f2bf(acc[j][r] + bv);
  }
}

// ---------------------------------------------------------------------------
// attn: logits = g*(2 q.p - |p|^2), softmax over 512, out[n,k,h,w] fp32.
// Block 512 thr, tile 64 pix x 512 protos; wave w owns protos [64w,64w+64).
// P fragments load directly from global chunked Pr (L1/L2-resident, 128KB)
// -> NO LDS staging of P, single barrier before softmax. Output stored
// straight from accumulators as f32x4 (lane's 4 acc regs = 4 consecutive
// pixels of one k-plane).
// ---------------------------------------------------------------------------
__global__ __launch_bounds__(512) void attn_kernel(const unsigned short* __restrict__ qbf,
                                                   const unsigned short* __restrict__ Pr,
                                                   const float* __restrict__ pn2,
                                                   const float* __restrict__ gptr,
                                                   float* __restrict__ out) {
  __shared__ __align__(16) unsigned short q_s[64 * 136];  // 17408 B
  float* red  = (float*)q_s;        // [8][64]  (overlay, used after barrier)
  float* rmx  = (float*)q_s + 512;  // [64]
  float* rinv = (float*)q_s + 576;  // [64]

  const int tid  = threadIdx.x;
  const int p0   = blockIdx.x * 64;
  const int nimg = p0 >> 12;
  const int hw0  = p0 & 4095;
  const int wave = tid >> 6, lane = tid & 63;
  const int l15 = lane & 15, l4 = lane >> 4;
  const float g = fabsf(gptr[0]);

  {  // stage q tile [64][128] bf16 -> LDS
    const int r = tid >> 3, c8 = tid & 7;
#pragma unroll
    for (int it = 0; it < 2; ++it) {
      const int col = c8 + 8 * it;
      s16x8 v = *(const s16x8*)(qbf + (size_t)(p0 + r) * DIM + 8 * col);
      *(s16x8*)&q_s[r * 136 + 8 * col] = v;
    }
  }
  __syncthreads();

  f32x4 acc[4][4];
#pragma unroll
  for (int i = 0; i < 4; ++i)
#pragma unroll
    for (int j = 0; j < 4; ++j)
#pragma unroll
      for (int r = 0; r < 4; ++r) acc[i][j][r] = 0.f;

#pragma unroll
  for (int ch = 0; ch < 4; ++ch) {
    s16x8 afr[4];
#pragma unroll
    for (int i = 0; i < 4; ++i)
      afr[i] = *(const s16x8*)&q_s[(16 * i + l15) * 136 + 32 * ch + 8 * l4];
    const unsigned short* pb = Pr + ((size_t)ch * NPROTO + 64 * wave + l15) * 32 + 8 * l4;
#pragma unroll
    for (int j = 0; j < 4; ++j) {
      s16x8 bfr = *(const s16x8*)(pb + (size_t)(16 * j) * 32);
#pragma unroll
      for (int i = 0; i < 4; ++i)
        acc[i][j] = __builtin_amdgcn_mfma_f32_16x16x32_bf16(afr[i], bfr, acc[i][j], 0, 0, 0);
    }
  }
  __syncthreads();  // q_s reads done; red overlay becomes safe

  // logits + row max. lane holds rows m=16i+4*l4+r, cols n=64w+16j+l15
  float pnv[4];
#pragma unroll
  for (int j = 0; j < 4; ++j) pnv[j] = pn2[64 * wave + 16 * j + l15];

#pragma unroll
  for (int i = 0; i < 4; ++i)
#pragma unroll
    for (int r = 0; r < 4; ++r) {
      float m = -1e30f;
#pragma unroll
      for (int j = 0; j < 4; ++j) {
        float lv = g * (2.f * acc[i][j][r] - pnv[j]);
        acc[i][j][r] = lv;
        m = fmaxf(m, lv);
      }
#pragma unroll
      for (int s = 1; s < 16; s <<= 1) m = fmaxf(m, __shfl_xor(m, s));
      if (l15 == 0) red[wave * 64 + 16 * i + 4 * l4 + r] = m;
    }
  __syncthreads();
  if (tid < 64) {
    float M = red[tid];
#pragma unroll
    for (int w = 1; w < 8; ++w) M = fmaxf(M, red[w * 64 + tid]);
    rmx[tid] = M;
  }
  __syncthreads();

#pragma unroll
  for (int i = 0; i < 4; ++i)
#pragma unroll
    for (int r = 0; r < 4; ++r) {
      const float M = rmx[16 * i + 4 * l4 + r];
      float s = 0.f;
#pragma unroll
      for (int j = 0; j < 4; ++j) {
        float e = __expf(acc[i][j][r] - M);
        acc[i][j][r] = e;
        s += e;
      }
#pragma unroll
      for (int t = 1; t < 16; t <<= 1) s += __shfl_xor(s, t);
      if (l15 == 0) red[wave * 64 + 16 * i + 4 * l4 + r] = s;
    }
  __syncthreads();
  if (tid < 64) {
    float S = 0.f;
#pragma unroll
    for (int w = 0; w < 8; ++w) S += red[w * 64 + tid];
    rinv[tid] = 1.f / S;
  }
  __syncthreads();

  float inv[4][4];
#pragma unroll
  for (int i = 0; i < 4; ++i)
#pragma unroll
    for (int r = 0; r < 4; ++r) inv[i][r] = rinv[16 * i + 4 * l4 + r];

  // direct fp32 stores: lane (i,j) -> plane n=64w+16j+l15, pixels 16i+4*l4..+3
  const size_t outbase = (size_t)nimg * NPROTO * HW + hw0;
#pragma unroll
  for (int j = 0; j < 4; ++j) {
    float* op = out + outbase + (size_t)(64 * wave + 16 * j + l15) * HW + 4 * l4;
#pragma unroll
    for (int i = 0; i < 4; ++i) {
      f32x4 o;
#pragma unroll
      for (int r = 0; r < 4; ++r) o[r] = acc[i][j][r] * inv[i][r];
      *(f32x4*)(op + 16 * i) = o;
    }
  }
}

extern "C" void kernel_launch(void* const* d_in, const int* in_sizes, int n_in,
                              void* d_out, int out_size, void* d_ws, size_t ws_size,
                              hipStream_t stream) {
  const float* x     = (const float*)d_in[0];
  const float* Wm    = (const float*)d_in[1];
  const float* bias  = (const float*)d_in[2];
  const float* prot  = (const float*)d_in[3];
  const float* gamma = (const float*)d_in[4];
  float* out = (float*)d_out;

  // ws: q bf16 16MiB | Pr 128KiB | Wr 64KiB | pn2 2KiB
  unsigned short* q_ws  = (unsigned short*)d_ws;
  unsigned short* P_ws  = (unsigned short*)((char*)d_ws + 16777216);
  unsigned short* W_ws  = (unsigned short*)((char*)d_ws + 16777216 + 131072);
  float*          pn2_w = (float*)((char*)d_ws + 16777216 + 131072 + 65536);

  prep_kernel<<<10, 256, 0, stream>>>(prot, Wm, P_ws, W_ws, pn2_w);
  proj_kernel<<<512, 512, 0, stream>>>(x, W_ws, bias, q_ws);
  attn_kernel<<<1024, 512, 0, stream>>>(q_ws, P_ws, pn2_w, gamma, out);
}

// Round 3
// 232.909 us; speedup vs baseline: 1.0662x; 1.0662x over previous
//
#include <hip/hip_runtime.h>

#define HW 4096
#define NCH 256
#define DIM 128
#define NPROTO 512

typedef __attribute__((ext_vector_type(4))) float f32x4;
typedef __attribute__((ext_vector_type(8))) short s16x8;
typedef __attribute__((ext_vector_type(4))) short s16x4;
typedef __attribute__((ext_vector_type(2))) unsigned u32x2;

__device__ __forceinline__ unsigned short f2bf(float f) {
  union { float f; unsigned u; } v; v.f = f;
  unsigned r = v.u + 0x7fffu + ((v.u >> 16) & 1u);
  return (unsigned short)(r >> 16);
}

// ---------------------------------------------------------------------------
// prep: blocks 0..7: prototypes -> bf16 chunked Pr[kc][n][32] (kc = d/32) +
//       p_norm2.  blocks 8..9: W -> bf16 chunked Wr[kc][d][32] (kc = c/32).
// 64B rows so MFMA fragments load directly from global:
//   frag(row, koff=8*l4) = base + (kc*ROWS + row)*32 + 8*l4   (bf16 units)
// ---------------------------------------------------------------------------
__global__ __launch_bounds__(256) void prep_kernel(const float* __restrict__ P,
                                                   const float* __restrict__ Wm,
                                                   unsigned short* __restrict__ Pr,
                                                   unsigned short* __restrict__ Wr,
                                                   float* __restrict__ pn2) {
  const int tid = threadIdx.x;
  if (blockIdx.x < 8) {
    const int n  = blockIdx.x * 64 + (tid >> 2);
    const int qt = tid & 3;
    const float* row = P + n * DIM + qt * 32;
    unsigned short* dst = Pr + ((size_t)qt * NPROTO + n) * 32;
    float ssq = 0.f;
#pragma unroll
    for (int u = 0; u < 8; ++u) {
      f32x4 v = *(const f32x4*)(row + 4 * u);
      ssq += v.x * v.x + v.y * v.y + v.z * v.z + v.w * v.w;
      dst[4 * u + 0] = f2bf(v.x);
      dst[4 * u + 1] = f2bf(v.y);
      dst[4 * u + 2] = f2bf(v.z);
      dst[4 * u + 3] = f2bf(v.w);
    }
    ssq += __shfl_xor(ssq, 1);
    ssq += __shfl_xor(ssq, 2);
    if (qt == 0) pn2[n] = ssq;
  } else {
#pragma unroll
    for (int it = 0; it < 2; ++it) {
      const int p  = (blockIdx.x - 8) * 256 + tid + 512 * it;  // 0..1023
      const int d  = p >> 3;
      const int ch = p & 7;
      const float* src = Wm + d * NCH + 32 * ch;
      unsigned short* dst = Wr + ((size_t)ch * DIM + d) * 32;
#pragma unroll
      for (int u = 0; u < 8; ++u) {
        f32x4 v = *(const f32x4*)(src + 4 * u);
        dst[4 * u + 0] = f2bf(v.x);
        dst[4 * u + 1] = f2bf(v.y);
        dst[4 * u + 2] = f2bf(v.z);
        dst[4 * u + 3] = f2bf(v.w);
      }
    }
  }
}

// ---------------------------------------------------------------------------
// fused: per block of 32 pixels (one image, contiguous hw run):
//   1) stage x [32 pix][256 ch] fp32->bf16 into LDS, XOR-swizzled slots
//   2) GEMM1 as q^T = W . x^T (A=W global, B=x LDS) -> q bf16 [32][128] LDS
//   3) GEMM2 q . P^T (A=q LDS, B=P global), logits = g*(2S - |p|^2)
//   4) softmax over 512, direct f32x4 stores from accumulators
// 512 threads = 8 waves. Swizzle slot(g,pix) = (g&24) | ((g ^ (pix>>1)) & 7)
// keeps both the b64 staging writes and the b128 fragment reads ~uniform.
// ---------------------------------------------------------------------------
__global__ __launch_bounds__(512) void fused_kernel(const float* __restrict__ x,
                                                    const unsigned short* __restrict__ Wr,
                                                    const float* __restrict__ bias,
                                                    const unsigned short* __restrict__ Pr,
                                                    const float* __restrict__ pn2,
                                                    const float* __restrict__ gptr,
                                                    float* __restrict__ out) {
  __shared__ __align__(16) char smem[25088];
  unsigned short* x_s = (unsigned short*)smem;            // [32][256] swizzled, 16384 B
  unsigned short* q_s = (unsigned short*)(smem + 16384);  // [32][136], 8704 B
  float* red  = (float*)smem;        // [8][32] overlay on x_s (dead after GEMM1)
  float* rmx  = (float*)smem + 256;  // [32]
  float* rinv = (float*)smem + 288;  // [32]

  const int tid  = threadIdx.x;
  const int p0   = blockIdx.x * 32;
  const int nimg = p0 >> 12;
  const int hw0  = p0 & 4095;
  const int wave = tid >> 6, lane = tid & 63;
  const int l15 = lane & 15, l4 = lane >> 4;
  const float g = fabsf(gptr[0]);

  // ---- 1) stage x: thread (f=pix quad, gg=ch group of 8, h=group half)
  {
    const int f  = tid & 7;
    const int gg = (tid >> 3) & 31;
    const int h  = tid >> 8;
    const float* src = x + (size_t)nimg * NCH * HW + hw0
                         + (size_t)(8 * gg + 4 * h) * HW + 4 * f;
    f32x4 v0 = *(const f32x4*)(src);
    f32x4 v1 = *(const f32x4*)(src + HW);
    f32x4 v2 = *(const f32x4*)(src + 2 * HW);
    f32x4 v3 = *(const f32x4*)(src + 3 * HW);
#pragma unroll
    for (int j = 0; j < 4; ++j) {
      const int pix  = 4 * f + j;
      const int slot = (gg & 24) | ((gg ^ (pix >> 1)) & 7);
      u32x2 wv;
      wv.x = (unsigned)f2bf(v0[j]) | ((unsigned)f2bf(v1[j]) << 16);
      wv.y = (unsigned)f2bf(v2[j]) | ((unsigned)f2bf(v3[j]) << 16);
      *(u32x2*)(x_s + pix * 256 + slot * 8 + 4 * h) = wv;  // 8B aligned
    }
  }
  __syncthreads();

  // ---- 2) GEMM1: wave w -> d-tiles {2(w&3), 2(w&3)+1}, pix-tile w>>2
  {
    const int mtb  = (wave & 3) * 2;
    const int nt   = wave >> 2;
    const int pixb = 16 * nt + l15;
    f32x4 qa0 = {0.f, 0.f, 0.f, 0.f};
    f32x4 qa1 = {0.f, 0.f, 0.f, 0.f};
#pragma unroll
    for (int kc = 0; kc < 8; ++kc) {
      const int gb   = 4 * kc + l4;
      const int slot = (gb & 24) | ((gb ^ (pixb >> 1)) & 7);
      s16x8 xb = *(const s16x8*)(x_s + pixb * 256 + slot * 8);
      const unsigned short* wb = Wr + (size_t)(kc * DIM + l15) * 32 + 8 * l4;
      s16x8 w0 = *(const s16x8*)(wb + (size_t)(16 * mtb) * 32);
      s16x8 w1 = *(const s16x8*)(wb + (size_t)(16 * (mtb + 1)) * 32);
      qa0 = __builtin_amdgcn_mfma_f32_16x16x32_bf16(w0, xb, qa0, 0, 0, 0);
      qa1 = __builtin_amdgcn_mfma_f32_16x16x32_bf16(w1, xb, qa1, 0, 0, 0);
    }
    // D rows = d = 16*mt + 4*l4 + r, cols = pix = pixb. 4 consecutive d -> b64
#pragma unroll
    for (int mm = 0; mm < 2; ++mm) {
      const int d0 = 16 * (mtb + mm) + 4 * l4;
      f32x4 qa = mm ? qa1 : qa0;
      f32x4 bv = *(const f32x4*)(bias + d0);
      s16x4 o;
#pragma unroll
      for (int r = 0; r < 4; ++r) o[r] = (short)f2bf(qa[r] + bv[r]);
      *(s16x4*)(q_s + pixb * 136 + d0) = o;  // 8B aligned (272B rows)
    }
  }
  __syncthreads();

  // ---- 3) GEMM2: wave w owns protos [64w, 64w+64)
  f32x4 acc[2][4];
#pragma unroll
  for (int i = 0; i < 2; ++i)
#pragma unroll
    for (int j = 0; j < 4; ++j)
#pragma unroll
      for (int r = 0; r < 4; ++r) acc[i][j][r] = 0.f;

#pragma unroll
  for (int kc = 0; kc < 4; ++kc) {
    s16x8 afr[2];
#pragma unroll
    for (int i = 0; i < 2; ++i)
      afr[i] = *(const s16x8*)(q_s + (16 * i + l15) * 136 + 32 * kc + 8 * l4);
    const unsigned short* pb = Pr + (size_t)(kc * NPROTO + 64 * wave + l15) * 32 + 8 * l4;
#pragma unroll
    for (int j = 0; j < 4; ++j) {
      s16x8 bfr = *(const s16x8*)(pb + (size_t)(16 * j) * 32);
#pragma unroll
      for (int i = 0; i < 2; ++i)
        acc[i][j] = __builtin_amdgcn_mfma_f32_16x16x32_bf16(afr[i], bfr, acc[i][j], 0, 0, 0);
    }
  }
  // no barrier needed: red overlays x_s, whose last reads were before the
  // post-GEMM1 barrier; q_s (read above) is a distinct region.

  // ---- 4) softmax. lane holds rows pix=16i+4*l4+r, cols n=64w+16j+l15
  float pnv[4];
#pragma unroll
  for (int j = 0; j < 4; ++j) pnv[j] = pn2[64 * wave + 16 * j + l15];

#pragma unroll
  for (int i = 0; i < 2; ++i)
#pragma unroll
    for (int r = 0; r < 4; ++r) {
      float m = -1e30f;
#pragma unroll
      for (int j = 0; j < 4; ++j) {
        float lv = g * (2.f * acc[i][j][r] - pnv[j]);
        acc[i][j][r] = lv;
        m = fmaxf(m, lv);
      }
#pragma unroll
      for (int s = 1; s < 16; s <<= 1) m = fmaxf(m, __shfl_xor(m, s));
      if (l15 == 0) red[wave * 32 + 16 * i + 4 * l4 + r] = m;
    }
  __syncthreads();
  if (tid < 32) {
    float M = red[tid];
#pragma unroll
    for (int w = 1; w < 8; ++w) M = fmaxf(M, red[w * 32 + tid]);
    rmx[tid] = M;
  }
  __syncthreads();

#pragma unroll
  for (int i = 0; i < 2; ++i)
#pragma unroll
    for (int r = 0; r < 4; ++r) {
      const float M = rmx[16 * i + 4 * l4 + r];
      float s = 0.f;
#pragma unroll
      for (int j = 0; j < 4; ++j) {
        float e = __expf(acc[i][j][r] - M);
        acc[i][j][r] = e;
        s += e;
      }
#pragma unroll
      for (int t = 1; t < 16; t <<= 1) s += __shfl_xor(s, t);
      if (l15 == 0) red[wave * 32 + 16 * i + 4 * l4 + r] = s;
    }
  __syncthreads();
  if (tid < 32) {
    float S = 0.f;
#pragma unroll
    for (int w = 0; w < 8; ++w) S += red[w * 32 + tid];
    rinv[tid] = 1.f / S;
  }
  __syncthreads();

  float inv[2][4];
#pragma unroll
  for (int i = 0; i < 2; ++i)
#pragma unroll
    for (int r = 0; r < 4; ++r) inv[i][r] = rinv[16 * i + 4 * l4 + r];

  const size_t outbase = (size_t)nimg * NPROTO * HW + hw0;
#pragma unroll
  for (int j = 0; j < 4; ++j) {
    float* op = out + outbase + (size_t)(64 * wave + 16 * j + l15) * HW + 4 * l4;
#pragma unroll
    for (int i = 0; i < 2; ++i) {
      f32x4 o;
#pragma unroll
      for (int r = 0; r < 4; ++r) o[r] = acc[i][j][r] * inv[i][r];
      *(f32x4*)(op + 16 * i) = o;
    }
  }
}

extern "C" void kernel_launch(void* const* d_in, const int* in_sizes, int n_in,
                              void* d_out, int out_size, void* d_ws, size_t ws_size,
                              hipStream_t stream) {
  const float* x     = (const float*)d_in[0];
  const float* Wm    = (const float*)d_in[1];
  const float* bias  = (const float*)d_in[2];
  const float* prot  = (const float*)d_in[3];
  const float* gamma = (const float*)d_in[4];
  float* out = (float*)d_out;

  // ws: Pr 128KiB | Wr 64KiB | pn2 2KiB   (q intermediate eliminated)
  unsigned short* P_ws  = (unsigned short*)d_ws;
  unsigned short* W_ws  = (unsigned short*)((char*)d_ws + 131072);
  float*          pn2_w = (float*)((char*)d_ws + 131072 + 65536);

  prep_kernel<<<10, 256, 0, stream>>>(prot, Wm, P_ws, W_ws, pn2_w);
  fused_kernel<<<2048, 512, 0, stream>>>(x, W_ws, bias, P_ws, pn2_w, gamma, out);
}